// Round 7
// baseline (173.768 us; speedup 1.0000x reference)
//
#include <hip/hip_runtime.h>

typedef __attribute__((ext_vector_type(8))) short bf16x8;
typedef __attribute__((ext_vector_type(4))) float f32x4;
typedef __attribute__((ext_vector_type(4))) unsigned uint4v;

#define SM_C 0.18033688011112042f  // 0.125 * log2(e)
#define MFMA16 __builtin_amdgcn_mfma_f32_16x16x32_bf16

__device__ __forceinline__ unsigned short f2bf(float f) {
  unsigned u = __builtin_bit_cast(unsigned, f);
  u += 0x7fffu + ((u >> 16) & 1u);
  return (unsigned short)(u >> 16);
}

__device__ __forceinline__ unsigned cvtpk(float lo, float hi) {
  unsigned r;
  asm volatile("v_cvt_pk_bf16_f32 %0, %1, %2" : "=v"(r) : "v"(lo), "v"(hi));
  return r;
}

__device__ __forceinline__ void gload16(const void* g, void* lds) {
  __builtin_amdgcn_global_load_lds(
      (const __attribute__((address_space(1))) void*)g,
      (__attribute__((address_space(3))) void*)lds, 16, 0, 0);
}

#define BARRIER __builtin_amdgcn_s_barrier()
#define LGKM0 asm volatile("s_waitcnt lgkmcnt(0)" ::: "memory")

// ---------------- x -> bf16 ----------------
__global__ __launch_bounds__(256) void cvt_x(const float* __restrict__ in,
                                             unsigned short* __restrict__ out,
                                             int n4) {
  int i = blockIdx.x * 256 + threadIdx.x;
  int stride = gridDim.x * 256;
  for (; i < n4; i += stride) {
    float4 v = ((const float4*)in)[i];
    unsigned short o0 = f2bf(v.x), o1 = f2bf(v.y), o2 = f2bf(v.z), o3 = f2bf(v.w);
    unsigned long long packed = (unsigned long long)o0 | ((unsigned long long)o1 << 16) |
                                ((unsigned long long)o2 << 32) | ((unsigned long long)o3 << 48);
    ((unsigned long long*)out)[i] = packed;
  }
}

// ---------------- W[K][N] f32 -> WT[N][K] bf16 ----------------
__global__ __launch_bounds__(256) void transpose_w(const float* __restrict__ W,
                                                   unsigned short* __restrict__ WT) {
  __shared__ float tile[32][33];
  int bx = blockIdx.x, by = blockIdx.y;
  int x = bx * 32 + threadIdx.x;
  for (int i = 0; i < 4; ++i) {
    int r = threadIdx.y + i * 8;
    tile[r][threadIdx.x] = W[(by * 32 + r) * 1024 + x];
  }
  __syncthreads();
  int nx = by * 32 + threadIdx.x;
  for (int i = 0; i < 4; ++i) {
    int r = threadIdx.y + i * 8;
    WT[(long)(bx * 32 + r) * 1024 + nx] = f2bf(tile[threadIdx.x][r]);
  }
}

// ---------------- V columns of QKV -> Vt[bh][hd][s_perm] ----------------
__global__ __launch_bounds__(256) void transpose_v(const unsigned short* __restrict__ QKV,
                                                   unsigned short* __restrict__ Vt) {
  __shared__ alignas(16) unsigned short tile[64][74];
  const int bid = blockIdx.x;
  const int st = bid & 31, bh = bid >> 5;
  const int b = bh >> 4, h = bh & 15;
  const int t = threadIdx.x;
  const int r = t >> 2, c16 = (t & 3) * 16;
  const unsigned short* src =
      QKV + ((long)(b * 2048 + st * 64 + r)) * 3072 + 2048 + h * 64 + c16;
  uint4v v0 = *(const uint4v*)src;
  uint4v v1 = *(const uint4v*)(src + 8);
  unsigned* dst32 = (unsigned*)&tile[r][c16];
  dst32[0] = v0[0]; dst32[1] = v0[1]; dst32[2] = v0[2]; dst32[3] = v0[3];
  dst32[4] = v1[0]; dst32[5] = v1[1]; dst32[6] = v1[2]; dst32[7] = v1[3];
  __syncthreads();
  const int lw = t & 63, w = t >> 6;
  const int vp = (lw & 32) | (((lw >> 2) & 3) << 3) | (((lw >> 4) & 1) << 2) | (lw & 3);
#pragma unroll
  for (int k = 0; k < 16; ++k) {
    int hd = w * 16 + k;
    Vt[((long)(bh * 64 + hd)) * 2048 + st * 64 + vp] = tile[lw][hd];
  }
}

// ---------------- GEMM v4: m201 8-phase skeleton -----------------------------
// C[M][N] = A[M][K] * BT[N][K]^T.  512 threads = 8 waves (2M x 4N), BK=64.
// Per phase: [vmcnt(N)][BAR][ds_read quadrant + stage unit(s)][BAR][lgkm(0)]
// [setprio(1) MFMA setprio(0)].  vmcnt never 0 in steady state.
// Stage units (1 gload/thread each) are interleaved stripe-sets matching
// per-wave consumption:  A-even = quarters{0,2} (m-half0 rows of both wm),
// A-odd = {1,3};  B units = 32-row (BN=256) / 16-row (BN=128) stripe pairs
// aligned to n-half boundaries.  FIFO issue order == consumption order.
template <int BN, int FP32OUT>
__global__ __launch_bounds__(512, 1) void gemm8(const unsigned short* __restrict__ A,
                                                const unsigned short* __restrict__ BT,
                                                unsigned short* __restrict__ Cb,
                                                float* __restrict__ Cf,
                                                const float* __restrict__ bias,
                                                int M, int N, int K) {
  constexpr int NR = BN / 64;   // n-frags per wave (4 or 2)
  constexpr int NH = NR / 2;    // n-frags per n-half (2 or 1)
  __shared__ alignas(16) unsigned short As[2][256 * 64];
  __shared__ alignas(16) unsigned short Bs[2][BN * 64];

  const int nbn = N / BN;
  const int tmg = (M / 256) / 8;
  const int bid = blockIdx.x;
  const int cc = bid >> 3, xc = bid & 7;
  const int tm = xc * tmg + cc / nbn, tn = cc % nbn;

  const int t = threadIdx.x, l = t & 63, wid = t >> 6;
  const int wm = wid >> 2, wn = wid & 3;
  const int lr = l & 15, lg = l >> 4;

  f32x4 acc[8][NR] = {};

  // staging geometry: thread t covers slot (t&7) of a row; source pre-swizzled
  // (slot ^ row&7), LDS dest linear (rule 21).  row&7 == (t>>3)&7 for all units.
  const int sq = t >> 3;
  const int sslot8 = ((t & 7) ^ (sq & 7)) * 8;
  const unsigned short* Ath = A + ((long)tm * 256 + sq) * K + sslot8;
  const unsigned short* Bth = BT + ((long)tn * BN) * K + sslot8;
  const int ldsAoff = sq * 64 + (t & 7) * 8;
  const int ldsB7 = (t & 7) * 8;
  // B stage-unit rows
  const int rbB = (BN == 256) ? (((t >> 8) << 6) + (sq & 31))    // 2x32-row stripes
                              : (((t >> 7) << 5) + (sq & 15));   // 4x16-row stripes

#define STGA(buf, q, kt) \
  gload16(Ath + (long)((q)*64) * K + (kt)*64, &As[buf][(q)*4096 + ldsAoff])
#define STGB(buf, rb, kt) \
  gload16(Bth + (long)(rb)*K + (kt)*64, &Bs[buf][(rb)*64 + ldsB7])

  const int NT = K >> 6;
  // prologue: FIFO order == steady-tile stage order
  if constexpr (BN == 256) {
    STGA(0, 0, 0); STGA(0, 2, 0);
    STGB(0, rbB, 0); STGB(0, rbB + 128, 0);
    STGB(0, rbB + 32, 0); STGB(0, rbB + 160, 0);
    STGA(0, 1, 0); STGA(0, 3, 0);
  } else {
    STGA(0, 0, 0); STGA(0, 2, 0);
    STGB(0, rbB, 0); STGB(0, rbB + 16, 0);
    STGA(0, 1, 0); STGA(0, 3, 0);
  }

  const int offk0 = ((0 + lg) ^ (lr & 7)) * 8;
  const int offk1 = ((4 + lg) ^ (lr & 7)) * 8;
  const int arow0 = (wm * 128 + lr) * 64;
  const int brow0 = (wn * (NR * 16) + lr) * 64;

#define DS_A(MH)                                                   \
  _Pragma("unroll") for (int m_ = 0; m_ < 4; ++m_) {               \
    const unsigned short* ap_ = Ac + arow0 + ((MH)*4 + m_) * 1024; \
    af[m_][0] = *(const bf16x8*)(ap_ + offk0);                     \
    af[m_][1] = *(const bf16x8*)(ap_ + offk1);                     \
  }
#define DS_B(NHI)                                                    \
  _Pragma("unroll") for (int n_ = 0; n_ < NH; ++n_) {                \
    const unsigned short* bp_ = Bc + brow0 + ((NHI)*NH + n_) * 1024; \
    bfr[n_][0] = *(const bf16x8*)(bp_ + offk0);                      \
    bfr[n_][1] = *(const bf16x8*)(bp_ + offk1);                      \
  }
#define MM(MH, NHI)                                                              \
  __builtin_amdgcn_s_setprio(1);                                                 \
  _Pragma("unroll") for (int m_ = 0; m_ < 4; ++m_)                               \
  _Pragma("unroll") for (int n_ = 0; n_ < NH; ++n_) {                            \
    acc[(MH)*4 + m_][(NHI)*NH + n_] =                                            \
        MFMA16(af[m_][0], bfr[n_][0], acc[(MH)*4 + m_][(NHI)*NH + n_], 0, 0, 0); \
    acc[(MH)*4 + m_][(NHI)*NH + n_] =                                            \
        MFMA16(af[m_][1], bfr[n_][1], acc[(MH)*4 + m_][(NHI)*NH + n_], 0, 0, 0); \
  }                                                                              \
  __builtin_amdgcn_s_setprio(0);

  for (int tt = 0; tt < NT; ++tt) {
    const unsigned short* Ac = As[tt & 1];
    const unsigned short* Bc = Bs[tt & 1];
    const int nb = (tt & 1) ^ 1;
    const int kt = tt + 1;
    const bool st = kt < NT;

    bf16x8 af[4][2];
    bf16x8 bfr[NH][2];

    // P0: quadrant (m0,n0).  Entering wait certifies A-even(t)+B-nhalf0(t).
    if constexpr (BN == 256) asm volatile("s_waitcnt vmcnt(4)" ::: "memory");
    else                     asm volatile("s_waitcnt vmcnt(3)" ::: "memory");
    BARRIER;
    DS_A(0);
    DS_B(0);
    if (st) { STGA(nb, 0, kt); STGA(nb, 2, kt); }
    if constexpr (BN == 256) asm volatile("s_waitcnt lgkmcnt(8)" ::: "memory");
    BARRIER;
    LGKM0;
    MM(0, 0);

    // P1: quadrant (m0,n1).  Needs B-nhalf1(t).
    if (st) asm volatile("s_waitcnt vmcnt(4)" ::: "memory");
    else    asm volatile("s_waitcnt vmcnt(2)" ::: "memory");
    BARRIER;
    DS_B(1);
    if (st) {
      if constexpr (BN == 256) { STGB(nb, rbB, kt); STGB(nb, rbB + 128, kt); }
      else                     { STGB(nb, rbB, kt); STGB(nb, rbB + 16, kt); }
    }
    BARRIER;
    LGKM0;
    MM(0, 1);

    // P2: quadrant (m1,n1).  Needs A-odd(t).
    if (st) asm volatile("s_waitcnt vmcnt(4)" ::: "memory");
    else    asm volatile("s_waitcnt vmcnt(0)" ::: "memory");
    BARRIER;
    DS_A(1);
    if (st) {
      if constexpr (BN == 256) { STGB(nb, rbB + 32, kt); STGB(nb, rbB + 160, kt); }
      else                     { STGA(nb, 1, kt); STGA(nb, 3, kt); }
    }
    BARRIER;
    LGKM0;
    MM(1, 1);

    // P3: quadrant (m1,n0).  Re-reads B-nhalf0 (already certified).
    BARRIER;
    DS_B(0);
    if (st) {
      if constexpr (BN == 256) { STGA(nb, 1, kt); STGA(nb, 3, kt); }
    }
    BARRIER;
    LGKM0;
    MM(1, 0);
  }
#undef DS_A
#undef DS_B
#undef MM
#undef STGA
#undef STGB

  // epilogue
  const long crow = (long)tm * 256 + wm * 128;
  const int ccol = tn * BN + wn * (NR * 16);
#pragma unroll
  for (int m = 0; m < 8; ++m)
#pragma unroll
    for (int n = 0; n < NR; ++n)
#pragma unroll
      for (int r = 0; r < 4; ++r) {
        long row = crow + m * 16 + lg * 4 + r;
        int col = ccol + n * 16 + lr;
        if (FP32OUT)
          Cf[row * N + col] = acc[m][n][r] + bias[col];
        else
          Cb[row * N + col] = f2bf(acc[m][n][r]);
      }
}

// ---------------- Flash attention tile body ----------------
template <int TWO>
__device__ __forceinline__ void attn_tile(
    const unsigned short* __restrict__ Kc, const unsigned short* __restrict__ Vc,
    int lr, int lg, bool mask0, bool mask1, int kv0, int q0row, int q1row,
    const bf16x8 (&qf)[2][2], f32x4 (&cacc)[2][4], float (&m_r)[2], float (&l_r)[2]) {
  constexpr int S0 = TWO ? 0 : 1;
  f32x4 p[2][4];
#pragma unroll
  for (int s = S0; s < 2; ++s)
#pragma unroll
    for (int g = 0; g < 4; ++g) p[s][g] = f32x4{0.f, 0.f, 0.f, 0.f};

  __builtin_amdgcn_s_setprio(1);
#pragma unroll
  for (int g = 0; g < 4; ++g) {
    const int key = g * 16 + lr;
    const int swz = (key & 7) << 3;
#pragma unroll
    for (int c = 0; c < 2; ++c) {
      bf16x8 kf = *(const bf16x8*)(Kc + key * 64 + ((c * 32 + lg * 8) ^ swz));
#pragma unroll
      for (int s = S0; s < 2; ++s)
        p[s][g] = MFMA16(kf, qf[s][c], p[s][g], 0, 0, 0);
    }
  }
  __builtin_amdgcn_s_setprio(0);

  if (TWO && mask0) {
#pragma unroll
    for (int g = 0; g < 4; ++g)
#pragma unroll
      for (int r = 0; r < 4; ++r)
        if (kv0 + g * 16 + lg * 4 + r > q0row) p[0][g][r] = -1e30f;
  }
  if (mask1) {
#pragma unroll
    for (int g = 0; g < 4; ++g)
#pragma unroll
      for (int r = 0; r < 4; ++r)
        if (kv0 + g * 16 + lg * 4 + r > q1row) p[1][g][r] = -1e30f;
  }

  unsigned pk[2][4][2];
#pragma unroll
  for (int s = S0; s < 2; ++s) {
    float mloc = p[s][0][0];
#pragma unroll
    for (int g = 0; g < 4; ++g)
#pragma unroll
      for (int r = 0; r < 4; ++r) mloc = fmaxf(mloc, p[s][g][r]);
    mloc = fmaxf(mloc, __shfl_xor(mloc, 16));
    mloc = fmaxf(mloc, __shfl_xor(mloc, 32));
    const bool defer = __all(mloc <= m_r[s] + 44.0f);
    const float mn = defer ? m_r[s] : fmaxf(m_r[s], mloc);
    const float nmc = -mn * SM_C;
    float rs = 0.f;
#pragma unroll
    for (int g = 0; g < 4; ++g)
#pragma unroll
      for (int r = 0; r < 4; ++r) {
        float e = __builtin_amdgcn_exp2f(__builtin_fmaf(p[s][g][r], SM_C, nmc));
        p[s][g][r] = e;
        rs += e;
      }
    rs += __shfl_xor(rs, 16);
    rs += __shfl_xor(rs, 32);
    if (defer) {
      l_r[s] += rs;
    } else {
      float alpha = __builtin_amdgcn_exp2f((m_r[s] - mn) * SM_C);
      l_r[s] = l_r[s] * alpha + rs;
      m_r[s] = mn;
      float alq[4];
#pragma unroll
      for (int r = 0; r < 4; ++r) alq[r] = __shfl(alpha, lg * 20 + r);
#pragma unroll
      for (int n = 0; n < 4; ++n)
#pragma unroll
        for (int r = 0; r < 4; ++r) cacc[s][n][r] *= alq[r];
    }
#pragma unroll
    for (int g = 0; g < 4; ++g) {
      pk[s][g][0] = cvtpk(p[s][g][0], p[s][g][1]);
      pk[s][g][1] = cvtpk(p[s][g][2], p[s][g][3]);
    }
  }

#pragma unroll
  for (int sl = 0; sl < 2; ++sl) {
    bf16x8 vf[4];
#pragma unroll
    for (int n = 0; n < 4; ++n) {
      const int hd = n * 16 + lr;
      vf[n] = *(const bf16x8*)(Vc + hd * 64 + ((sl * 32 + lg * 8) ^ ((hd & 7) << 3)));
    }
    __builtin_amdgcn_s_setprio(1);
#pragma unroll
    for (int s = S0; s < 2; ++s) {
      uint4v pw = {pk[s][2 * sl][0], pk[s][2 * sl][1], pk[s][2 * sl + 1][0], pk[s][2 * sl + 1][1]};
      bf16x8 pa = __builtin_bit_cast(bf16x8, pw);
#pragma unroll
      for (int n = 0; n < 4; ++n)
        cacc[s][n] = MFMA16(pa, vf[n], cacc[s][n], 0, 0, 0);
    }
    __builtin_amdgcn_s_setprio(0);
  }
}

// ---------------- Flash attention (paired causal strips) ----------------
__global__ __launch_bounds__(256, 4) void flash_attn(const unsigned short* __restrict__ QKV,
                                                     const unsigned short* __restrict__ Vt,
                                                     unsigned short* __restrict__ Ctx) {
  __shared__ alignas(16) unsigned short Ks[2][64 * 64];
  __shared__ alignas(16) unsigned short Vs[2][64 * 64];
  const int bid = blockIdx.x;
  const int qt = bid >> 6;
  const int bh = bid & 63;
  const int b = bh >> 4, h = bh & 15;
  const int t = threadIdx.x, l = t & 63, w = t >> 6;
  const int lr = l & 15, lg = l >> 4;
  const long rowbase = (long)b * 2048;
  const int colbase = h * 64;
  const int q0 = qt * 64 + w * 16;
  const int q1 = (31 - qt) * 64 + w * 16;
  const int q0row = q0 + lr, q1row = q1 + lr;
  const int nkv = 32 - qt;

  bf16x8 qf[2][2];
#pragma unroll
  for (int c = 0; c < 2; ++c) {
    qf[0][c] = *(const bf16x8*)(QKV + (rowbase + q0 + lr) * 3072 + colbase + c * 32 + lg * 8);
    qf[1][c] = *(const bf16x8*)(QKV + (rowbase + q1 + lr) * 3072 + colbase + c * 32 + lg * 8);
  }

  f32x4 cacc[2][4];
  float m_r[2], l_r[2];
#pragma unroll
  for (int s = 0; s < 2; ++s) {
    m_r[s] = -1e30f;
    l_r[s] = 0.f;
#pragma unroll
    for (int n = 0; n < 4; ++n) cacc[s][n] = f32x4{0.f, 0.f, 0.f, 0.f};
  }

  const int srow = w * 16 + (l >> 3);
  const int scol = (l & 7) * 8;
  const int kswz = scol ^ ((srow & 7) << 3);
  const unsigned short* kp = QKV + (rowbase + srow) * 3072 + 1024 + colbase + kswz;
  const unsigned short* vp = Vt + ((long)(bh * 64 + srow)) * 2048 + kswz;
  unsigned short* ksd0 = &Ks[0][(w * 16) * 64];
  unsigned short* vsd0 = &Vs[0][(w * 16) * 64];

#define STAGE(buf)                                    \
  do {                                                \
    gload16(kp, ksd0 + (buf) * 4096);                 \
    gload16(kp + 8 * 3072, ksd0 + (buf) * 4096 + 512);\
    gload16(vp, vsd0 + (buf) * 4096);                 \
    gload16(vp + 8 * 2048, vsd0 + (buf) * 4096 + 512);\
    kp += 64 * 3072;                                  \
    vp += 64;                                         \
  } while (0)

  STAGE(0);
  __syncthreads();

  int j = 0;
  for (; j <= qt; ++j) {
    const int cur = j & 1;
    if (j + 1 < nkv) STAGE(cur ^ 1);
    attn_tile<1>(Ks[cur], Vs[cur], lr, lg, j == qt, false, j * 64, q0row, q1row,
                 qf, cacc, m_r, l_r);
    __syncthreads();
  }
  for (; j < nkv; ++j) {
    const int cur = j & 1;
    if (j + 1 < nkv) STAGE(cur ^ 1);
    attn_tile<0>(Ks[cur], Vs[cur], lr, lg, false, j == nkv - 1, j * 64, q0row, q1row,
                 qf, cacc, m_r, l_r);
    __syncthreads();
  }
#undef STAGE

#pragma unroll
  for (int s = 0; s < 2; ++s) {
    float invl = 1.f / l_r[s];
    float ilq[4];
#pragma unroll
    for (int r = 0; r < 4; ++r) ilq[r] = __shfl(invl, lg * 20 + r);
    const int qs = (s == 0) ? q0 : q1;
#pragma unroll
    for (int n = 0; n < 4; ++n)
#pragma unroll
      for (int r = 0; r < 4; ++r) {
        long row = rowbase + qs + lg * 4 + r;
        Ctx[row * 1024 + colbase + n * 16 + lr] = f2bf(cacc[s][n][r] * ilq[r]);
      }
  }
}

extern "C" void kernel_launch(void* const* d_in, const int* in_sizes, int n_in,
                              void* d_out, int out_size, void* d_ws, size_t ws_size,
                              hipStream_t stream) {
  (void)in_sizes; (void)n_in; (void)out_size; (void)ws_size;
  const float* x  = (const float*)d_in[0];
  const float* Wq = (const float*)d_in[1];
  const float* Wk = (const float*)d_in[2];
  const float* Wv = (const float*)d_in[3];
  const float* Wo = (const float*)d_in[4];
  const float* bo = (const float*)d_in[5];
  float* out = (float*)d_out;

  unsigned short* ws = (unsigned short*)d_ws;
  unsigned short* xb  = ws;                       // 8192*1024 (dead after QKV GEMM)
  unsigned short* Vt  = ws;                       // aliases xb: written after GEMM
  unsigned short* WqT = ws + 8388608;
  unsigned short* WkT = WqT + 1048576;
  unsigned short* WvT = WkT + 1048576;
  unsigned short* WoT = WvT + 1048576;
  unsigned short* QKV = WoT + 1048576;            // 8192*3072
  unsigned short* Ctx = QKV + 25165824;           // 8192*1024

  cvt_x<<<2048, 256, 0, stream>>>(x, xb, 8192 * 1024 / 4);

  dim3 tb(32, 8), tg(32, 32);
  transpose_w<<<tg, tb, 0, stream>>>(Wq, WqT);
  transpose_w<<<tg, tb, 0, stream>>>(Wk, WkT);
  transpose_w<<<tg, tb, 0, stream>>>(Wv, WvT);
  transpose_w<<<tg, tb, 0, stream>>>(Wo, WoT);

  // fused QKV projection: M=8192, N=3072, K=1024 (256x256 tiles, 384 blocks)
  gemm8<256, 0><<<384, 512, 0, stream>>>(xb, WqT, QKV, nullptr, nullptr,
                                         8192, 3072, 1024);

  // V -> Vt[bh][hd][s_perm]  (xb dead; Vt aliases it)
  transpose_v<<<2048, 256, 0, stream>>>(QKV, Vt);

  // flash attention: 64 bh x 16 paired-strip blocks
  flash_attn<<<1024, 256, 0, stream>>>(QKV, Vt, Ctx);

  // output projection + bias: fp32 out (256x128 tiles, 256 blocks exact)
  gemm8<128, 1><<<256, 512, 0, stream>>>(Ctx, WoT, nullptr, out, bo,
                                         8192, 1024, 1024);
}

// Round 8
// 160.174 us; speedup vs baseline: 1.0849x; 1.0849x over previous
//
#include <hip/hip_runtime.h>

typedef __attribute__((ext_vector_type(8))) short bf16x8;
typedef __attribute__((ext_vector_type(4))) float f32x4;
typedef __attribute__((ext_vector_type(4))) unsigned uint4v;

#define SM_C 0.18033688011112042f  // 0.125 * log2(e)
#define MFMA16 __builtin_amdgcn_mfma_f32_16x16x32_bf16

__device__ __forceinline__ unsigned short f2bf(float f) {
  unsigned u = __builtin_bit_cast(unsigned, f);
  u += 0x7fffu + ((u >> 16) & 1u);
  return (unsigned short)(u >> 16);
}

__device__ __forceinline__ unsigned cvtpk(float lo, float hi) {
  unsigned r;
  asm volatile("v_cvt_pk_bf16_f32 %0, %1, %2" : "=v"(r) : "v"(lo), "v"(hi));
  return r;
}

__device__ __forceinline__ void gload16(const void* g, void* lds) {
  __builtin_amdgcn_global_load_lds(
      (const __attribute__((address_space(1))) void*)g,
      (__attribute__((address_space(3))) void*)lds, 16, 0, 0);
}

#define BARRIER __builtin_amdgcn_s_barrier()
#define LGKM0 asm volatile("s_waitcnt lgkmcnt(0)" ::: "memory")

// ---------------- x -> bf16 ----------------
__global__ __launch_bounds__(256) void cvt_x(const float* __restrict__ in,
                                             unsigned short* __restrict__ out,
                                             int n4) {
  int i = blockIdx.x * 256 + threadIdx.x;
  int stride = gridDim.x * 256;
  for (; i < n4; i += stride) {
    float4 v = ((const float4*)in)[i];
    unsigned short o0 = f2bf(v.x), o1 = f2bf(v.y), o2 = f2bf(v.z), o3 = f2bf(v.w);
    unsigned long long packed = (unsigned long long)o0 | ((unsigned long long)o1 << 16) |
                                ((unsigned long long)o2 << 32) | ((unsigned long long)o3 << 48);
    ((unsigned long long*)out)[i] = packed;
  }
}

// ---------------- 4x W[K][N] f32 -> WT[N][K] bf16 (fused) ----------------
__global__ __launch_bounds__(256) void transpose_w4(const float* __restrict__ W0,
                                                    const float* __restrict__ W1,
                                                    const float* __restrict__ W2,
                                                    const float* __restrict__ W3,
                                                    unsigned short* __restrict__ WT) {
  __shared__ float tile[32][33];
  const int z = blockIdx.z;
  const float* W = (z == 0) ? W0 : (z == 1) ? W1 : (z == 2) ? W2 : W3;
  unsigned short* WTo = WT + (size_t)z * 1048576;
  int bx = blockIdx.x, by = blockIdx.y;
  int x = bx * 32 + threadIdx.x;
  for (int i = 0; i < 4; ++i) {
    int r = threadIdx.y + i * 8;
    tile[r][threadIdx.x] = W[(by * 32 + r) * 1024 + x];
  }
  __syncthreads();
  int nx = by * 32 + threadIdx.x;
  for (int i = 0; i < 4; ++i) {
    int r = threadIdx.y + i * 8;
    WTo[(long)(bx * 32 + r) * 1024 + nx] = f2bf(tile[threadIdx.x][r]);
  }
}

// ---------------- V columns of QKV -> Vt[bh][hd][s_perm] ----------------
__global__ __launch_bounds__(256) void transpose_v(const unsigned short* __restrict__ QKV,
                                                   unsigned short* __restrict__ Vt) {
  __shared__ alignas(16) unsigned short tile[64][74];
  const int bid = blockIdx.x;
  const int st = bid & 31, bh = bid >> 5;
  const int b = bh >> 4, h = bh & 15;
  const int t = threadIdx.x;
  const int r = t >> 2, c16 = (t & 3) * 16;
  const unsigned short* src =
      QKV + ((long)(b * 2048 + st * 64 + r)) * 3072 + 2048 + h * 64 + c16;
  uint4v v0 = *(const uint4v*)src;
  uint4v v1 = *(const uint4v*)(src + 8);
  unsigned* dst32 = (unsigned*)&tile[r][c16];
  dst32[0] = v0[0]; dst32[1] = v0[1]; dst32[2] = v0[2]; dst32[3] = v0[3];
  dst32[4] = v1[0]; dst32[5] = v1[1]; dst32[6] = v1[2]; dst32[7] = v1[3];
  __syncthreads();
  const int lw = t & 63, w = t >> 6;
  const int vp = (lw & 32) | (((lw >> 2) & 3) << 3) | (((lw >> 4) & 1) << 2) | (lw & 3);
#pragma unroll
  for (int k = 0; k < 16; ++k) {
    int hd = w * 16 + k;
    Vt[((long)(bh * 64 + hd)) * 2048 + st * 64 + vp] = tile[lw][hd];
  }
}

// ---------------- GEMM v5: 2-phase/K-tile, B-frags live across tile ----------
// C[M][N] = A[M][K] * BT[N][K]^T.  BM=256, BN=NR*64.  512 thr = 8 waves (2Mx4N),
// wave-tile 128 x NR*16.  BK=64.  Per K-tile: 2 phases:
//   P0: [vmcnt(2)][BAR][ds A-half0 (8) + B-all (2NR); stage B(t+1) NR units]
//       [BAR][lgkm0][4xNRx2 MFMA]
//   P1: [vmcnt(NR)][BAR][ds A-half1 (8); stage A(t+1) units 0,2,1,3]
//       [BAR][lgkm0][4xNRx2 MFMA]
// FIFO per tile: B0..B_{NR-1}, A0, A2, A1, A3  (entry vmcnt(2) certifies
// B-all+A0+A2; mid vmcnt(NR) certifies A1,A3).  Never 0 in steady state.
template <int NR, int FP32OUT>
__global__ __launch_bounds__(512, 1) void gemm2ph(const unsigned short* __restrict__ A,
                                                  const unsigned short* __restrict__ BT,
                                                  unsigned short* __restrict__ Cb,
                                                  float* __restrict__ Cf,
                                                  const float* __restrict__ bias,
                                                  int M, int N, int K) {
  constexpr int BN = NR * 64;
  __shared__ alignas(16) unsigned short As[2][256 * 64];
  __shared__ alignas(16) unsigned short Bs[2][BN * 64];

  const int nbn = N / BN;
  const int tmg = (M / 256) / 8;
  const int cc = blockIdx.x >> 3, xc = blockIdx.x & 7;
  const int tm = xc * tmg + cc / nbn, tn = cc % nbn;

  const int t = threadIdx.x, l = t & 63, wid = t >> 6;
  const int wm = wid >> 2, wn = wid & 3;
  const int lr = l & 15, lg = l >> 4;

  f32x4 acc[8][NR] = {};

  // staging: thread t covers (row sq, slot t&7) of each 64-row unit;
  // source pre-swizzled (slot ^ row&7), LDS dest linear (rule 21).
  const int sq = t >> 3;
  const int sslot8 = ((t & 7) ^ (sq & 7)) * 8;
  const unsigned short* Ath = A + ((long)tm * 256 + sq) * K + sslot8;
  const unsigned short* Bth = BT + ((long)tn * BN + sq) * K + sslot8;
  const int ldsoff = sq * 64 + (t & 7) * 8;

#define STGA(buf, q, kt) \
  gload16(Ath + (long)((q)*64) * K + (kt)*64, &As[buf][(q)*4096 + ldsoff])
#define STGB(buf, u, kt) \
  gload16(Bth + (long)((u)*64) * K + (kt)*64, &Bs[buf][(u)*4096 + ldsoff])

  const int NT = K >> 6;
  // prologue (FIFO == steady order)
#pragma unroll
  for (int u = 0; u < NR; ++u) STGB(0, u, 0);
  STGA(0, 0, 0); STGA(0, 2, 0); STGA(0, 1, 0); STGA(0, 3, 0);

  const int offk0 = (lg ^ (lr & 7)) * 8;
  const int offk1 = ((4 + lg) ^ (lr & 7)) * 8;
  const int arow0 = (wm * 128 + lr) * 64;
  const int brow0 = (wn * (NR * 16) + lr) * 64;

#define DS_A(MH)                                                   \
  _Pragma("unroll") for (int m_ = 0; m_ < 4; ++m_) {               \
    const unsigned short* ap_ = Ac + arow0 + ((MH)*4 + m_) * 1024; \
    af[m_][0] = *(const bf16x8*)(ap_ + offk0);                     \
    af[m_][1] = *(const bf16x8*)(ap_ + offk1);                     \
  }
#define DS_B_ALL                                          \
  _Pragma("unroll") for (int n_ = 0; n_ < NR; ++n_) {     \
    const unsigned short* bp_ = Bc + brow0 + n_ * 1024;   \
    bfr[n_][0] = *(const bf16x8*)(bp_ + offk0);           \
    bfr[n_][1] = *(const bf16x8*)(bp_ + offk1);           \
  }
#define MM(MH)                                                              \
  __builtin_amdgcn_s_setprio(1);                                            \
  _Pragma("unroll") for (int m_ = 0; m_ < 4; ++m_)                          \
  _Pragma("unroll") for (int n_ = 0; n_ < NR; ++n_) {                       \
    acc[(MH)*4 + m_][n_] = MFMA16(af[m_][0], bfr[n_][0],                    \
                                  acc[(MH)*4 + m_][n_], 0, 0, 0);           \
    acc[(MH)*4 + m_][n_] = MFMA16(af[m_][1], bfr[n_][1],                    \
                                  acc[(MH)*4 + m_][n_], 0, 0, 0);           \
  }                                                                         \
  __builtin_amdgcn_s_setprio(0);

  for (int tt = 0; tt < NT; ++tt) {
    const unsigned short* Ac = As[tt & 1];
    const unsigned short* Bc = Bs[tt & 1];
    const int nb = (tt & 1) ^ 1;
    const int kt = tt + 1;
    const bool st = kt < NT;

    bf16x8 af[4][2];
    bf16x8 bfr[NR][2];

    // P0
    asm volatile("s_waitcnt vmcnt(2)" ::: "memory");
    BARRIER;
    DS_A(0);
    DS_B_ALL;
    if (st) {
#pragma unroll
      for (int u = 0; u < NR; ++u) STGB(nb, u, kt);
    }
    BARRIER;
    LGKM0;
    MM(0);

    // P1
    if (st) {
      if constexpr (NR == 3) asm volatile("s_waitcnt vmcnt(3)" ::: "memory");
      else                   asm volatile("s_waitcnt vmcnt(2)" ::: "memory");
    } else {
      asm volatile("s_waitcnt vmcnt(0)" ::: "memory");
    }
    BARRIER;
    DS_A(1);
    if (st) { STGA(nb, 0, kt); STGA(nb, 2, kt); STGA(nb, 1, kt); STGA(nb, 3, kt); }
    BARRIER;
    LGKM0;
    MM(1);
  }
#undef DS_A
#undef DS_B_ALL
#undef MM
#undef STGA
#undef STGB

  // epilogue
  const long crow = (long)tm * 256 + wm * 128;
  const int ccol = tn * BN + wn * (NR * 16);
#pragma unroll
  for (int m = 0; m < 8; ++m)
#pragma unroll
    for (int n = 0; n < NR; ++n)
#pragma unroll
      for (int r = 0; r < 4; ++r) {
        long row = crow + m * 16 + lg * 4 + r;
        int col = ccol + n * 16 + lr;
        if (FP32OUT)
          Cf[row * N + col] = acc[m][n][r] + bias[col];
        else
          Cb[row * N + col] = f2bf(acc[m][n][r]);
      }
}

// ---------------- Flash attention tile body ----------------
template <int TWO>
__device__ __forceinline__ void attn_tile(
    const unsigned short* __restrict__ Kc, const unsigned short* __restrict__ Vc,
    int lr, int lg, bool mask0, bool mask1, int kv0, int q0row, int q1row,
    const bf16x8 (&qf)[2][2], f32x4 (&cacc)[2][4], float (&m_r)[2], float (&l_r)[2]) {
  constexpr int S0 = TWO ? 0 : 1;
  f32x4 p[2][4];
#pragma unroll
  for (int s = S0; s < 2; ++s)
#pragma unroll
    for (int g = 0; g < 4; ++g) p[s][g] = f32x4{0.f, 0.f, 0.f, 0.f};

  __builtin_amdgcn_s_setprio(1);
#pragma unroll
  for (int g = 0; g < 4; ++g) {
    const int key = g * 16 + lr;
    const int swz = (key & 7) << 3;
#pragma unroll
    for (int c = 0; c < 2; ++c) {
      bf16x8 kf = *(const bf16x8*)(Kc + key * 64 + ((c * 32 + lg * 8) ^ swz));
#pragma unroll
      for (int s = S0; s < 2; ++s)
        p[s][g] = MFMA16(kf, qf[s][c], p[s][g], 0, 0, 0);
    }
  }
  __builtin_amdgcn_s_setprio(0);

  if (TWO && mask0) {
#pragma unroll
    for (int g = 0; g < 4; ++g)
#pragma unroll
      for (int r = 0; r < 4; ++r)
        if (kv0 + g * 16 + lg * 4 + r > q0row) p[0][g][r] = -1e30f;
  }
  if (mask1) {
#pragma unroll
    for (int g = 0; g < 4; ++g)
#pragma unroll
      for (int r = 0; r < 4; ++r)
        if (kv0 + g * 16 + lg * 4 + r > q1row) p[1][g][r] = -1e30f;
  }

  unsigned pk[2][4][2];
#pragma unroll
  for (int s = S0; s < 2; ++s) {
    float mloc = p[s][0][0];
#pragma unroll
    for (int g = 0; g < 4; ++g)
#pragma unroll
      for (int r = 0; r < 4; ++r) mloc = fmaxf(mloc, p[s][g][r]);
    mloc = fmaxf(mloc, __shfl_xor(mloc, 16));
    mloc = fmaxf(mloc, __shfl_xor(mloc, 32));
    const bool defer = __all(mloc <= m_r[s] + 44.0f);
    const float mn = defer ? m_r[s] : fmaxf(m_r[s], mloc);
    const float nmc = -mn * SM_C;
    float rs = 0.f;
#pragma unroll
    for (int g = 0; g < 4; ++g)
#pragma unroll
      for (int r = 0; r < 4; ++r) {
        float e = __builtin_amdgcn_exp2f(__builtin_fmaf(p[s][g][r], SM_C, nmc));
        p[s][g][r] = e;
        rs += e;
      }
    rs += __shfl_xor(rs, 16);
    rs += __shfl_xor(rs, 32);
    if (defer) {
      l_r[s] += rs;
    } else {
      float alpha = __builtin_amdgcn_exp2f((m_r[s] - mn) * SM_C);
      l_r[s] = l_r[s] * alpha + rs;
      m_r[s] = mn;
      float alq[4];
#pragma unroll
      for (int r = 0; r < 4; ++r) alq[r] = __shfl(alpha, lg * 20 + r);
#pragma unroll
      for (int n = 0; n < 4; ++n)
#pragma unroll
        for (int r = 0; r < 4; ++r) cacc[s][n][r] *= alq[r];
    }
#pragma unroll
    for (int g = 0; g < 4; ++g) {
      pk[s][g][0] = cvtpk(p[s][g][0], p[s][g][1]);
      pk[s][g][1] = cvtpk(p[s][g][2], p[s][g][3]);
    }
  }

#pragma unroll
  for (int sl = 0; sl < 2; ++sl) {
    bf16x8 vf[4];
#pragma unroll
    for (int n = 0; n < 4; ++n) {
      const int hd = n * 16 + lr;
      vf[n] = *(const bf16x8*)(Vc + hd * 64 + ((sl * 32 + lg * 8) ^ ((hd & 7) << 3)));
    }
    __builtin_amdgcn_s_setprio(1);
#pragma unroll
    for (int s = S0; s < 2; ++s) {
      uint4v pw = {pk[s][2 * sl][0], pk[s][2 * sl][1], pk[s][2 * sl + 1][0], pk[s][2 * sl + 1][1]};
      bf16x8 pa = __builtin_bit_cast(bf16x8, pw);
#pragma unroll
      for (int n = 0; n < 4; ++n)
        cacc[s][n] = MFMA16(pa, vf[n], cacc[s][n], 0, 0, 0);
    }
    __builtin_amdgcn_s_setprio(0);
  }
}

// ---------------- Flash attention (paired causal strips) ----------------
__global__ __launch_bounds__(256, 4) void flash_attn(const unsigned short* __restrict__ QKV,
                                                     const unsigned short* __restrict__ Vt,
                                                     unsigned short* __restrict__ Ctx) {
  __shared__ alignas(16) unsigned short Ks[2][64 * 64];
  __shared__ alignas(16) unsigned short Vs[2][64 * 64];
  const int bid = blockIdx.x;
  const int qt = bid >> 6;
  const int bh = bid & 63;
  const int b = bh >> 4, h = bh & 15;
  const int t = threadIdx.x, l = t & 63, w = t >> 6;
  const int lr = l & 15, lg = l >> 4;
  const long rowbase = (long)b * 2048;
  const int colbase = h * 64;
  const int q0 = qt * 64 + w * 16;
  const int q1 = (31 - qt) * 64 + w * 16;
  const int q0row = q0 + lr, q1row = q1 + lr;
  const int nkv = 32 - qt;

  bf16x8 qf[2][2];
#pragma unroll
  for (int c = 0; c < 2; ++c) {
    qf[0][c] = *(const bf16x8*)(QKV + (rowbase + q0 + lr) * 3072 + colbase + c * 32 + lg * 8);
    qf[1][c] = *(const bf16x8*)(QKV + (rowbase + q1 + lr) * 3072 + colbase + c * 32 + lg * 8);
  }

  f32x4 cacc[2][4];
  float m_r[2], l_r[2];
#pragma unroll
  for (int s = 0; s < 2; ++s) {
    m_r[s] = -1e30f;
    l_r[s] = 0.f;
#pragma unroll
    for (int n = 0; n < 4; ++n) cacc[s][n] = f32x4{0.f, 0.f, 0.f, 0.f};
  }

  const int srow = w * 16 + (l >> 3);
  const int scol = (l & 7) * 8;
  const int kswz = scol ^ ((srow & 7) << 3);
  const unsigned short* kp = QKV + (rowbase + srow) * 3072 + 1024 + colbase + kswz;
  const unsigned short* vp = Vt + ((long)(bh * 64 + srow)) * 2048 + kswz;
  unsigned short* ksd0 = &Ks[0][(w * 16) * 64];
  unsigned short* vsd0 = &Vs[0][(w * 16) * 64];

#define STAGE(buf)                                    \
  do {                                                \
    gload16(kp, ksd0 + (buf) * 4096);                 \
    gload16(kp + 8 * 3072, ksd0 + (buf) * 4096 + 512);\
    gload16(vp, vsd0 + (buf) * 4096);                 \
    gload16(vp + 8 * 2048, vsd0 + (buf) * 4096 + 512);\
    kp += 64 * 3072;                                  \
    vp += 64;                                         \
  } while (0)

  STAGE(0);
  __syncthreads();

  int j = 0;
  for (; j <= qt; ++j) {
    const int cur = j & 1;
    if (j + 1 < nkv) STAGE(cur ^ 1);
    attn_tile<1>(Ks[cur], Vs[cur], lr, lg, j == qt, false, j * 64, q0row, q1row,
                 qf, cacc, m_r, l_r);
    __syncthreads();
  }
  for (; j < nkv; ++j) {
    const int cur = j & 1;
    if (j + 1 < nkv) STAGE(cur ^ 1);
    attn_tile<0>(Ks[cur], Vs[cur], lr, lg, false, j == nkv - 1, j * 64, q0row, q1row,
                 qf, cacc, m_r, l_r);
    __syncthreads();
  }
#undef STAGE

#pragma unroll
  for (int s = 0; s < 2; ++s) {
    float invl = 1.f / l_r[s];
    float ilq[4];
#pragma unroll
    for (int r = 0; r < 4; ++r) ilq[r] = __shfl(invl, lg * 20 + r);
    const int qs = (s == 0) ? q0 : q1;
#pragma unroll
    for (int n = 0; n < 4; ++n)
#pragma unroll
      for (int r = 0; r < 4; ++r) {
        long row = rowbase + qs + lg * 4 + r;
        Ctx[row * 1024 + colbase + n * 16 + lr] = f2bf(cacc[s][n][r] * ilq[r]);
      }
  }
}

extern "C" void kernel_launch(void* const* d_in, const int* in_sizes, int n_in,
                              void* d_out, int out_size, void* d_ws, size_t ws_size,
                              hipStream_t stream) {
  (void)in_sizes; (void)n_in; (void)out_size; (void)ws_size;
  const float* x  = (const float*)d_in[0];
  const float* Wq = (const float*)d_in[1];
  const float* Wk = (const float*)d_in[2];
  const float* Wv = (const float*)d_in[3];
  const float* Wo = (const float*)d_in[4];
  const float* bo = (const float*)d_in[5];
  float* out = (float*)d_out;

  unsigned short* ws = (unsigned short*)d_ws;
  unsigned short* xb  = ws;                       // 8192*1024 (dead after QKV GEMM)
  unsigned short* Vt  = ws;                       // aliases xb: written after GEMM
  unsigned short* WqT = ws + 8388608;
  unsigned short* WkT = WqT + 1048576;
  unsigned short* WvT = WkT + 1048576;
  unsigned short* WoT = WvT + 1048576;
  unsigned short* QKV = WoT + 1048576;            // 8192*3072
  unsigned short* Ctx = QKV + 25165824;           // 8192*1024

  cvt_x<<<2048, 256, 0, stream>>>(x, xb, 8192 * 1024 / 4);

  dim3 tb(32, 8), tg(32, 32, 4);
  transpose_w4<<<tg, tb, 0, stream>>>(Wq, Wk, Wv, Wo, WqT);

  // fused QKV projection: M=8192, N=3072, K=1024 (256x192 tiles, 512 blocks = 2 rounds)
  gemm2ph<3, 0><<<512, 512, 0, stream>>>(xb, WqT, QKV, nullptr, nullptr,
                                         8192, 3072, 1024);

  // V -> Vt[bh][hd][s_perm]  (xb dead; Vt aliases it)
  transpose_v<<<2048, 256, 0, stream>>>(QKV, Vt);

  // flash attention: 64 bh x 16 paired-strip blocks
  flash_attn<<<1024, 256, 0, stream>>>(QKV, Vt, Ctx);

  // output projection + bias: fp32 out (256x128 tiles, 256 blocks = 1 round)
  gemm2ph<2, 1><<<256, 512, 0, stream>>>(Ctx, WoT, nullptr, out, bo,
                                         8192, 1024, 1024);
}

// Round 9
// 158.234 us; speedup vs baseline: 1.0982x; 1.0123x over previous
//
#include <hip/hip_runtime.h>

typedef __attribute__((ext_vector_type(8))) short bf16x8;
typedef __attribute__((ext_vector_type(4))) float f32x4;
typedef __attribute__((ext_vector_type(4))) unsigned uint4v;

#define SM_C 0.18033688011112042f  // 0.125 * log2(e)
#define MFMA16 __builtin_amdgcn_mfma_f32_16x16x32_bf16

__device__ __forceinline__ unsigned short f2bf(float f) {
  unsigned u = __builtin_bit_cast(unsigned, f);
  u += 0x7fffu + ((u >> 16) & 1u);
  return (unsigned short)(u >> 16);
}

__device__ __forceinline__ unsigned cvtpk(float lo, float hi) {
  unsigned r;
  asm volatile("v_cvt_pk_bf16_f32 %0, %1, %2" : "=v"(r) : "v"(lo), "v"(hi));
  return r;
}

__device__ __forceinline__ void gload16(const void* g, void* lds) {
  __builtin_amdgcn_global_load_lds(
      (const __attribute__((address_space(1))) void*)g,
      (__attribute__((address_space(3))) void*)lds, 16, 0, 0);
}

#define BARRIER __builtin_amdgcn_s_barrier()
#define LGKM0 asm volatile("s_waitcnt lgkmcnt(0)" ::: "memory")

// ---------------- x -> bf16 ----------------
__global__ __launch_bounds__(256) void cvt_x(const float* __restrict__ in,
                                             unsigned short* __restrict__ out,
                                             int n4) {
  int i = blockIdx.x * 256 + threadIdx.x;
  int stride = gridDim.x * 256;
  for (; i < n4; i += stride) {
    float4 v = ((const float4*)in)[i];
    unsigned short o0 = f2bf(v.x), o1 = f2bf(v.y), o2 = f2bf(v.z), o3 = f2bf(v.w);
    unsigned long long packed = (unsigned long long)o0 | ((unsigned long long)o1 << 16) |
                                ((unsigned long long)o2 << 32) | ((unsigned long long)o3 << 48);
    ((unsigned long long*)out)[i] = packed;
  }
}

// ---------------- 4x W[K][N] f32 -> WT[N][K] bf16 (fused) ----------------
__global__ __launch_bounds__(256) void transpose_w4(const float* __restrict__ W0,
                                                    const float* __restrict__ W1,
                                                    const float* __restrict__ W2,
                                                    const float* __restrict__ W3,
                                                    unsigned short* __restrict__ WT) {
  __shared__ float tile[32][33];
  const int z = blockIdx.z;
  const float* W = (z == 0) ? W0 : (z == 1) ? W1 : (z == 2) ? W2 : W3;
  unsigned short* WTo = WT + (size_t)z * 1048576;
  int bx = blockIdx.x, by = blockIdx.y;
  int x = bx * 32 + threadIdx.x;
  for (int i = 0; i < 4; ++i) {
    int r = threadIdx.y + i * 8;
    tile[r][threadIdx.x] = W[(by * 32 + r) * 1024 + x];
  }
  __syncthreads();
  int nx = by * 32 + threadIdx.x;
  for (int i = 0; i < 4; ++i) {
    int r = threadIdx.y + i * 8;
    WTo[(long)(bx * 32 + r) * 1024 + nx] = f2bf(tile[threadIdx.x][r]);
  }
}

// ---------------- V columns of QKV -> Vt[bh][hd][s_perm] ----------------
__global__ __launch_bounds__(256) void transpose_v(const unsigned short* __restrict__ QKV,
                                                   unsigned short* __restrict__ Vt) {
  __shared__ alignas(16) unsigned short tile[64][74];
  const int bid = blockIdx.x;
  const int st = bid & 31, bh = bid >> 5;
  const int b = bh >> 4, h = bh & 15;
  const int t = threadIdx.x;
  const int r = t >> 2, c16 = (t & 3) * 16;
  const unsigned short* src =
      QKV + ((long)(b * 2048 + st * 64 + r)) * 3072 + 2048 + h * 64 + c16;
  uint4v v0 = *(const uint4v*)src;
  uint4v v1 = *(const uint4v*)(src + 8);
  unsigned* dst32 = (unsigned*)&tile[r][c16];
  dst32[0] = v0[0]; dst32[1] = v0[1]; dst32[2] = v0[2]; dst32[3] = v0[3];
  dst32[4] = v1[0]; dst32[5] = v1[1]; dst32[6] = v1[2]; dst32[7] = v1[3];
  __syncthreads();
  const int lw = t & 63, w = t >> 6;
  const int vp = (lw & 32) | (((lw >> 2) & 3) << 3) | (((lw >> 4) & 1) << 2) | (lw & 3);
#pragma unroll
  for (int k = 0; k < 16; ++k) {
    int hd = w * 16 + k;
    Vt[((long)(bh * 64 + hd)) * 2048 + st * 64 + vp] = tile[lw][hd];
  }
}

// ---------------- GEMM v6: A triple-buffer, B double-buffer, 1 vmcnt/K-tile -
// C[M][N] = A[M][K] * BT[N][K]^T.  BM=256, BN=NR*64.  512 thr = 8 waves (2Mx4N).
// Per K-tile t (2 MFMA phases):
//   P0: [vmcnt(4) — retires A(t)x4+B(t)xNR; leaves A(t+1)x4][BAR_A]
//       ds A-half0(8) + B-all(2NR); stage B(t+1)xNR  [BAR_B][lgkm0][MM0]
//   P1: ds A-half1(8); stage A(t+2)x4               [BAR_C][lgkm0][MM1]
// FIFO: ...[A(t)x4][B(t)xNR][A(t+1)x4][B(t+1)xNR][A(t+2)x4]... — A-depth 3
// phases, B-depth 2; never drained in steady state (vmcnt(0) last tile only).
// Stage-write hazards: all reads of the target buffer completed via each
// wave's lgkm0 before its MM of tile t-1, which precedes BAR_A(t) < issue.
template <int NR, int FP32OUT>
__global__ __launch_bounds__(512, 1) void gemm3b(const unsigned short* __restrict__ A,
                                                 const unsigned short* __restrict__ BT,
                                                 unsigned short* __restrict__ Cb,
                                                 float* __restrict__ Cf,
                                                 const float* __restrict__ bias,
                                                 int M, int N, int K) {
  constexpr int BN = NR * 64;
  __shared__ alignas(16) unsigned short As[3][256 * 64];
  __shared__ alignas(16) unsigned short Bs[2][BN * 64];

  const int nbn = N / BN;
  const int tmg = (M / 256) / 8;
  const int cc = blockIdx.x >> 3, xc = blockIdx.x & 7;
  const int tm = xc * tmg + cc / nbn, tn = cc % nbn;

  const int t = threadIdx.x, l = t & 63, wid = t >> 6;
  const int wm = wid >> 2, wn = wid & 3;
  const int lr = l & 15, lg = l >> 4;

  f32x4 acc[8][NR] = {};

  // staging: thread t covers (row sq, slot t&7) of each 64-row unit;
  // source pre-swizzled (slot ^ row&7), LDS dest linear (rule 21).
  const int sq = t >> 3;
  const int sslot8 = ((t & 7) ^ (sq & 7)) * 8;
  const unsigned short* Ath = A + ((long)tm * 256 + sq) * K + sslot8;
  const unsigned short* Bth = BT + ((long)tn * BN + sq) * K + sslot8;
  const int ldsoff = sq * 64 + (t & 7) * 8;

#define STGA(buf, q, kt) \
  gload16(Ath + (long)((q)*64) * K + (kt)*64, &As[buf][(q)*4096 + ldsoff])
#define STGB(buf, u, kt) \
  gload16(Bth + (long)((u)*64) * K + (kt)*64, &Bs[buf][(u)*4096 + ldsoff])

  const int NT = K >> 6;
  // prologue FIFO: A(0)x4, B(0)xNR, A(1)x4
#pragma unroll
  for (int q = 0; q < 4; ++q) STGA(0, q, 0);
#pragma unroll
  for (int u = 0; u < NR; ++u) STGB(0, u, 0);
#pragma unroll
  for (int q = 0; q < 4; ++q) STGA(1, q, 1);

  const int offk0 = (lg ^ (lr & 7)) * 8;
  const int offk1 = ((4 + lg) ^ (lr & 7)) * 8;
  const int arow0 = (wm * 128 + lr) * 64;
  const int brow0 = (wn * (NR * 16) + lr) * 64;

#define DS_A(MH)                                                   \
  _Pragma("unroll") for (int m_ = 0; m_ < 4; ++m_) {               \
    const unsigned short* ap_ = Ac + arow0 + ((MH)*4 + m_) * 1024; \
    af[m_][0] = *(const bf16x8*)(ap_ + offk0);                     \
    af[m_][1] = *(const bf16x8*)(ap_ + offk1);                     \
  }
#define DS_B_ALL                                          \
  _Pragma("unroll") for (int n_ = 0; n_ < NR; ++n_) {     \
    const unsigned short* bp_ = Bc + brow0 + n_ * 1024;   \
    bfr[n_][0] = *(const bf16x8*)(bp_ + offk0);           \
    bfr[n_][1] = *(const bf16x8*)(bp_ + offk1);           \
  }
#define MM(MH)                                                              \
  __builtin_amdgcn_s_setprio(1);                                            \
  _Pragma("unroll") for (int m_ = 0; m_ < 4; ++m_)                          \
  _Pragma("unroll") for (int n_ = 0; n_ < NR; ++n_) {                       \
    acc[(MH)*4 + m_][n_] = MFMA16(af[m_][0], bfr[n_][0],                    \
                                  acc[(MH)*4 + m_][n_], 0, 0, 0);           \
    acc[(MH)*4 + m_][n_] = MFMA16(af[m_][1], bfr[n_][1],                    \
                                  acc[(MH)*4 + m_][n_], 0, 0, 0);           \
  }                                                                         \
  __builtin_amdgcn_s_setprio(0);

  int cur3 = 0;   // tt % 3
  int stg3 = 2;   // (tt+2) % 3
  for (int tt = 0; tt < NT; ++tt) {
    const unsigned short* Ac = As[cur3];
    const unsigned short* Bc = Bs[tt & 1];

    bf16x8 af[4][2];
    bf16x8 bfr[NR][2];

    // ---- P0 ----
    if (tt == NT - 1) asm volatile("s_waitcnt vmcnt(0)" ::: "memory");
    else              asm volatile("s_waitcnt vmcnt(4)" ::: "memory");
    BARRIER;  // BAR_A
    DS_A(0);
    DS_B_ALL;
    if (tt + 1 < NT) {
      const int nbB = (tt + 1) & 1;
#pragma unroll
      for (int u = 0; u < NR; ++u) STGB(nbB, u, tt + 1);
    }
    BARRIER;  // BAR_B
    LGKM0;
    MM(0);

    // ---- P1 (no entry wait/barrier: reads certified buffers) ----
    DS_A(1);
    if (tt + 2 < NT) {
#pragma unroll
      for (int q = 0; q < 4; ++q) STGA(stg3, q, tt + 2);
    }
    BARRIER;  // BAR_C
    LGKM0;
    MM(1);

    cur3 = (cur3 == 2) ? 0 : cur3 + 1;
    stg3 = (stg3 == 2) ? 0 : stg3 + 1;
  }
#undef DS_A
#undef DS_B_ALL
#undef MM
#undef STGA
#undef STGB

  // epilogue
  const long crow = (long)tm * 256 + wm * 128;
  const int ccol = tn * BN + wn * (NR * 16);
#pragma unroll
  for (int m = 0; m < 8; ++m)
#pragma unroll
    for (int n = 0; n < NR; ++n)
#pragma unroll
      for (int r = 0; r < 4; ++r) {
        long row = crow + m * 16 + lg * 4 + r;
        int col = ccol + n * 16 + lr;
        if (FP32OUT)
          Cf[row * N + col] = acc[m][n][r] + bias[col];
        else
          Cb[row * N + col] = f2bf(acc[m][n][r]);
      }
}

// ---------------- Flash attention tile body ----------------
template <int TWO>
__device__ __forceinline__ void attn_tile(
    const unsigned short* __restrict__ Kc, const unsigned short* __restrict__ Vc,
    int lr, int lg, bool mask0, bool mask1, int kv0, int q0row, int q1row,
    const bf16x8 (&qf)[2][2], f32x4 (&cacc)[2][4], float (&m_r)[2], float (&l_r)[2]) {
  constexpr int S0 = TWO ? 0 : 1;
  f32x4 p[2][4];
#pragma unroll
  for (int s = S0; s < 2; ++s)
#pragma unroll
    for (int g = 0; g < 4; ++g) p[s][g] = f32x4{0.f, 0.f, 0.f, 0.f};

  __builtin_amdgcn_s_setprio(1);
#pragma unroll
  for (int g = 0; g < 4; ++g) {
    const int key = g * 16 + lr;
    const int swz = (key & 7) << 3;
#pragma unroll
    for (int c = 0; c < 2; ++c) {
      bf16x8 kf = *(const bf16x8*)(Kc + key * 64 + ((c * 32 + lg * 8) ^ swz));
#pragma unroll
      for (int s = S0; s < 2; ++s)
        p[s][g] = MFMA16(kf, qf[s][c], p[s][g], 0, 0, 0);
    }
  }
  __builtin_amdgcn_s_setprio(0);

  if (TWO && mask0) {
#pragma unroll
    for (int g = 0; g < 4; ++g)
#pragma unroll
      for (int r = 0; r < 4; ++r)
        if (kv0 + g * 16 + lg * 4 + r > q0row) p[0][g][r] = -1e30f;
  }
  if (mask1) {
#pragma unroll
    for (int g = 0; g < 4; ++g)
#pragma unroll
      for (int r = 0; r < 4; ++r)
        if (kv0 + g * 16 + lg * 4 + r > q1row) p[1][g][r] = -1e30f;
  }

  unsigned pk[2][4][2];
#pragma unroll
  for (int s = S0; s < 2; ++s) {
    float mloc = p[s][0][0];
#pragma unroll
    for (int g = 0; g < 4; ++g)
#pragma unroll
      for (int r = 0; r < 4; ++r) mloc = fmaxf(mloc, p[s][g][r]);
    mloc = fmaxf(mloc, __shfl_xor(mloc, 16));
    mloc = fmaxf(mloc, __shfl_xor(mloc, 32));
    const bool defer = __all(mloc <= m_r[s] + 44.0f);
    const float mn = defer ? m_r[s] : fmaxf(m_r[s], mloc);
    const float nmc = -mn * SM_C;
    float rs = 0.f;
#pragma unroll
    for (int g = 0; g < 4; ++g)
#pragma unroll
      for (int r = 0; r < 4; ++r) {
        float e = __builtin_amdgcn_exp2f(__builtin_fmaf(p[s][g][r], SM_C, nmc));
        p[s][g][r] = e;
        rs += e;
      }
    rs += __shfl_xor(rs, 16);
    rs += __shfl_xor(rs, 32);
    if (defer) {
      l_r[s] += rs;
    } else {
      float alpha = __builtin_amdgcn_exp2f((m_r[s] - mn) * SM_C);
      l_r[s] = l_r[s] * alpha + rs;
      m_r[s] = mn;
      float alq[4];
#pragma unroll
      for (int r = 0; r < 4; ++r) alq[r] = __shfl(alpha, lg * 20 + r);
#pragma unroll
      for (int n = 0; n < 4; ++n)
#pragma unroll
        for (int r = 0; r < 4; ++r) cacc[s][n][r] *= alq[r];
    }
#pragma unroll
    for (int g = 0; g < 4; ++g) {
      pk[s][g][0] = cvtpk(p[s][g][0], p[s][g][1]);
      pk[s][g][1] = cvtpk(p[s][g][2], p[s][g][3]);
    }
  }

#pragma unroll
  for (int sl = 0; sl < 2; ++sl) {
    bf16x8 vf[4];
#pragma unroll
    for (int n = 0; n < 4; ++n) {
      const int hd = n * 16 + lr;
      vf[n] = *(const bf16x8*)(Vc + hd * 64 + ((sl * 32 + lg * 8) ^ ((hd & 7) << 3)));
    }
    __builtin_amdgcn_s_setprio(1);
#pragma unroll
    for (int s = S0; s < 2; ++s) {
      uint4v pw = {pk[s][2 * sl][0], pk[s][2 * sl][1], pk[s][2 * sl + 1][0], pk[s][2 * sl + 1][1]};
      bf16x8 pa = __builtin_bit_cast(bf16x8, pw);
#pragma unroll
      for (int n = 0; n < 4; ++n)
        cacc[s][n] = MFMA16(pa, vf[n], cacc[s][n], 0, 0, 0);
    }
    __builtin_amdgcn_s_setprio(0);
  }
}

// ---------------- Flash attention (paired causal strips) ----------------
__global__ __launch_bounds__(256, 4) void flash_attn(const unsigned short* __restrict__ QKV,
                                                     const unsigned short* __restrict__ Vt,
                                                     unsigned short* __restrict__ Ctx) {
  __shared__ alignas(16) unsigned short Ks[2][64 * 64];
  __shared__ alignas(16) unsigned short Vs[2][64 * 64];
  const int bid = blockIdx.x;
  const int qt = bid >> 6;
  const int bh = bid & 63;
  const int b = bh >> 4, h = bh & 15;
  const int t = threadIdx.x, l = t & 63, w = t >> 6;
  const int lr = l & 15, lg = l >> 4;
  const long rowbase = (long)b * 2048;
  const int colbase = h * 64;
  const int q0 = qt * 64 + w * 16;
  const int q1 = (31 - qt) * 64 + w * 16;
  const int q0row = q0 + lr, q1row = q1 + lr;
  const int nkv = 32 - qt;

  bf16x8 qf[2][2];
#pragma unroll
  for (int c = 0; c < 2; ++c) {
    qf[0][c] = *(const bf16x8*)(QKV + (rowbase + q0 + lr) * 3072 + colbase + c * 32 + lg * 8);
    qf[1][c] = *(const bf16x8*)(QKV + (rowbase + q1 + lr) * 3072 + colbase + c * 32 + lg * 8);
  }

  f32x4 cacc[2][4];
  float m_r[2], l_r[2];
#pragma unroll
  for (int s = 0; s < 2; ++s) {
    m_r[s] = -1e30f;
    l_r[s] = 0.f;
#pragma unroll
    for (int n = 0; n < 4; ++n) cacc[s][n] = f32x4{0.f, 0.f, 0.f, 0.f};
  }

  const int srow = w * 16 + (l >> 3);
  const int scol = (l & 7) * 8;
  const int kswz = scol ^ ((srow & 7) << 3);
  const unsigned short* kp = QKV + (rowbase + srow) * 3072 + 1024 + colbase + kswz;
  const unsigned short* vp = Vt + ((long)(bh * 64 + srow)) * 2048 + kswz;
  unsigned short* ksd0 = &Ks[0][(w * 16) * 64];
  unsigned short* vsd0 = &Vs[0][(w * 16) * 64];

#define STAGE(buf)                                    \
  do {                                                \
    gload16(kp, ksd0 + (buf) * 4096);                 \
    gload16(kp + 8 * 3072, ksd0 + (buf) * 4096 + 512);\
    gload16(vp, vsd0 + (buf) * 4096);                 \
    gload16(vp + 8 * 2048, vsd0 + (buf) * 4096 + 512);\
    kp += 64 * 3072;                                  \
    vp += 64;                                         \
  } while (0)

  STAGE(0);
  __syncthreads();

  int j = 0;
  for (; j <= qt; ++j) {
    const int cur = j & 1;
    if (j + 1 < nkv) STAGE(cur ^ 1);
    attn_tile<1>(Ks[cur], Vs[cur], lr, lg, j == qt, false, j * 64, q0row, q1row,
                 qf, cacc, m_r, l_r);
    __syncthreads();
  }
  for (; j < nkv; ++j) {
    const int cur = j & 1;
    if (j + 1 < nkv) STAGE(cur ^ 1);
    attn_tile<0>(Ks[cur], Vs[cur], lr, lg, false, j == nkv - 1, j * 64, q0row, q1row,
                 qf, cacc, m_r, l_r);
    __syncthreads();
  }
#undef STAGE

#pragma unroll
  for (int s = 0; s < 2; ++s) {
    float invl = 1.f / l_r[s];
    float ilq[4];
#pragma unroll
    for (int r = 0; r < 4; ++r) ilq[r] = __shfl(invl, lg * 20 + r);
    const int qs = (s == 0) ? q0 : q1;
#pragma unroll
    for (int n = 0; n < 4; ++n)
#pragma unroll
      for (int r = 0; r < 4; ++r) {
        long row = rowbase + qs + lg * 4 + r;
        Ctx[row * 1024 + colbase + n * 16 + lr] = f2bf(cacc[s][n][r] * ilq[r]);
      }
  }
}

extern "C" void kernel_launch(void* const* d_in, const int* in_sizes, int n_in,
                              void* d_out, int out_size, void* d_ws, size_t ws_size,
                              hipStream_t stream) {
  (void)in_sizes; (void)n_in; (void)out_size; (void)ws_size;
  const float* x  = (const float*)d_in[0];
  const float* Wq = (const float*)d_in[1];
  const float* Wk = (const float*)d_in[2];
  const float* Wv = (const float*)d_in[3];
  const float* Wo = (const float*)d_in[4];
  const float* bo = (const float*)d_in[5];
  float* out = (float*)d_out;

  unsigned short* ws = (unsigned short*)d_ws;
  unsigned short* xb  = ws;                       // 8192*1024 (dead after QKV GEMM)
  unsigned short* Vt  = ws;                       // aliases xb: written after GEMM
  unsigned short* WqT = ws + 8388608;
  unsigned short* WkT = WqT + 1048576;
  unsigned short* WvT = WkT + 1048576;
  unsigned short* WoT = WvT + 1048576;
  unsigned short* QKV = WoT + 1048576;            // 8192*3072
  unsigned short* Ctx = QKV + 25165824;           // 8192*1024

  cvt_x<<<2048, 256, 0, stream>>>(x, xb, 8192 * 1024 / 4);

  dim3 tb(32, 8), tg(32, 32, 4);
  transpose_w4<<<tg, tb, 0, stream>>>(Wq, Wk, Wv, Wo, WqT);

  // fused QKV projection: M=8192, N=3072, K=1024 (256x192 tiles, 512 blocks = 2 rounds)
  gemm3b<3, 0><<<512, 512, 0, stream>>>(xb, WqT, QKV, nullptr, nullptr,
                                        8192, 3072, 1024);

  // V -> Vt[bh][hd][s_perm]  (xb dead; Vt aliases it)
  transpose_v<<<2048, 256, 0, stream>>>(QKV, Vt);

  // flash attention: 64 bh x 16 paired-strip blocks
  flash_attn<<<1024, 256, 0, stream>>>(QKV, Vt, Ctx);

  // output projection + bias: fp32 out (256x128 tiles, 256 blocks = 1 round)
  gemm3b<2, 1><<<256, 512, 0, stream>>>(Ctx, WoT, nullptr, out, bo,
                                        8192, 1024, 1024);
}